// Round 1
// baseline (429.120 us; speedup 1.0000x reference)
//
#include <hip/hip_runtime.h>

// IDWT (Haar, stride-2 transposed conv, grouped):
//   x: [B, 4C, H, W] f32, filters: [4,2,2] f32
//   out[b, c, 2h+p, 2w+q] = sum_s x[b, s*C+c, h, w] * f[s, p, q]
// B=16, 4C=256 (C=64), H=W=128 -> out [16, 64, 256, 256]

constexpr int B = 16;
constexpr int C = 64;
constexpr int H = 128;
constexpr int W = 128;
constexpr int W4 = W / 4;                 // 32 quads per row
constexpr long N_THREADS = (long)B * C * H * W4;   // 4,194,304

__global__ __launch_bounds__(256) void idwt_kernel(
    const float* __restrict__ x,
    const float* __restrict__ f,
    float* __restrict__ out)
{
    const int idx = blockIdx.x * 256 + threadIdx.x;
    if (idx >= N_THREADS) return;

    // idx -> (b, c, h, w4); all dims are powers of two
    const int w4 = idx & (W4 - 1);        // 5 bits
    const int h  = (idx >> 5) & (H - 1);  // 7 bits
    const int c  = (idx >> 12) & (C - 1); // 6 bits
    const int b  = idx >> 18;

    const long sStride = (long)C * H * W;                       // subband stride
    const long inBase  = (((long)b * 4 * C + c) * H + h) * W + (long)w4 * 4;

    const float4 va = *(const float4*)(x + inBase);
    const float4 vb = *(const float4*)(x + inBase + sStride);
    const float4 vc = *(const float4*)(x + inBase + 2 * sStride);
    const float4 vd = *(const float4*)(x + inBase + 3 * sStride);

    // filters[s][p][q], flat: f[s*4 + p*2 + q] -- uniform addresses -> s_load
    const float f00 = f[0],  f01 = f[1],  f02 = f[2],  f03 = f[3];
    const float f10 = f[4],  f11 = f[5],  f12 = f[6],  f13 = f[7];
    const float f20 = f[8],  f21 = f[9],  f22 = f[10], f23 = f[11];
    const float f30 = f[12], f31 = f[13], f32 = f[14], f33 = f[15];

    const float av[4] = {va.x, va.y, va.z, va.w};
    const float bv[4] = {vb.x, vb.y, vb.z, vb.w};
    const float cv[4] = {vc.x, vc.y, vc.z, vc.w};
    const float dv[4] = {vd.x, vd.y, vd.z, vd.w};

    float r0[8], r1[8];
    #pragma unroll
    for (int j = 0; j < 4; ++j) {
        const float a = av[j], bb = bv[j], cc = cv[j], dd = dv[j];
        r0[2*j]     = a*f00 + bb*f10 + cc*f20 + dd*f30;   // p=0,q=0
        r0[2*j + 1] = a*f01 + bb*f11 + cc*f21 + dd*f31;   // p=0,q=1
        r1[2*j]     = a*f02 + bb*f12 + cc*f22 + dd*f32;   // p=1,q=0
        r1[2*j + 1] = a*f03 + bb*f13 + cc*f23 + dd*f33;   // p=1,q=1
    }

    // output: rows 2h and 2h+1, cols 8*w4 .. 8*w4+7 (contiguous)
    const long outBase = (((long)b * C + c) * (2 * H) + (long)2 * h) * (2 * W)
                         + (long)w4 * 8;
    *(float4*)(out + outBase)               = make_float4(r0[0], r0[1], r0[2], r0[3]);
    *(float4*)(out + outBase + 4)           = make_float4(r0[4], r0[5], r0[6], r0[7]);
    *(float4*)(out + outBase + 2 * W)       = make_float4(r1[0], r1[1], r1[2], r1[3]);
    *(float4*)(out + outBase + 2 * W + 4)   = make_float4(r1[4], r1[5], r1[6], r1[7]);
}

extern "C" void kernel_launch(void* const* d_in, const int* in_sizes, int n_in,
                              void* d_out, int out_size, void* d_ws, size_t ws_size,
                              hipStream_t stream) {
    const float* x = (const float*)d_in[0];
    const float* f = (const float*)d_in[1];
    float* out = (float*)d_out;

    const int threads = 256;
    const int blocks = (int)((N_THREADS + threads - 1) / threads);  // 16384
    idwt_kernel<<<blocks, threads, 0, stream>>>(x, f, out);
}